// Round 10
// baseline (10132.678 us; speedup 1.0000x reference)
//
#include <hip/hip_runtime.h>
#include <hip/hip_bf16.h>

// ---------------------------------------------------------------------------
// DEQ layer, MI355X round 9.
//  - Evidence: ~10us per graph node; 88 nodes -> ~880us of gap. BK=128 gemm
//    regressed (~+60us, matches m132); sq_kernel 80-block latency-bound.
//  - Changes:
//    * andergemm1: anderson(t) fused as PROLOGUE of gemm1. Each of the 8
//      column-chunk blocks redundantly computes anderson for its own 64 rows
//      (race-free-by-value: identical inputs -> identical stores), writes
//      Xh slot + zc, __syncthreads (vmcnt drain), then verbatim r5 BK=64
//      gemm1. Warm-up via modes; F2===F1 phantom slot redirect (r7/r8-
//      verified). 3 nodes/iter -> 2. Nodes 88 -> 64.
//    * GEMMs reverted to verified BK=64. sq split-K x8 (576 blocks).
// ---------------------------------------------------------------------------

#define B_ROWS 2048
#define D_LAT  256
#define D_CTX  256
#define D_HID  1024
#define KCAT   512
#define SLOT   (B_ROWS * D_LAT)
#define NRING  7

#define AS1 __attribute__((address_space(1)))
#define AS3 __attribute__((address_space(3)))

typedef __bf16 bf16x8 __attribute__((ext_vector_type(8)));
typedef float f32x4 __attribute__((ext_vector_type(4)));
typedef unsigned short u16;

// phantom position 2 (X2===X1, F2===F1) redirects to slot 1 (r7/r8-verified)
__device__ __forceinline__ int rdslot(int p) { return (p == 2) ? 1 : (p % NRING); }

// ---------------- init ------------------------------------------------------
__global__ void init_kernel(const float* __restrict__ ctx,
                            __hip_bfloat16* __restrict__ zc,
                            float* __restrict__ G1p, float* __restrict__ G2,
                            float* __restrict__ T1, float* __restrict__ M1,
                            float* __restrict__ T2, float* __restrict__ M2,
                            float* __restrict__ Xh, float* __restrict__ vA,
                            float* __restrict__ uA) {
  int i = blockIdx.x * 256 + threadIdx.x;
  if (i < B_ROWS * KCAT) {
    int b = i >> 9, c = i & 511;
    float v = (c < 256) ? 0.0f : ctx[b * 256 + (c - 256)];
    zc[i] = __float2bfloat16(v);
  }
  if (i < 512 * 512) { G1p[i] = 0.0f; T1[i] = 0.0f; M1[i] = 0.0f; }
  if (i < 256 * 256) { G2[i] = 0.0f; T2[i] = 0.0f; M2[i] = 0.0f; }
  if (i < SLOT) Xh[i] = 0.0f;
  if (i < KCAT) vA[i] = 0.0f;
  if (i < D_LAT) uA[i] = 1.0f;
}

// ---------------- Gram build, split-K x8 (verified r5) ---------------------
__global__ __launch_bounds__(256) void gram_kernel(
    const float* __restrict__ W1, const float* __restrict__ W2,
    float* __restrict__ G1p, float* __restrict__ G2) {
  __shared__ float As[32][65];
  __shared__ float Bs[32][65];
  const int tid = threadIdx.x;
  const int tx = tid & 15, ty = tid >> 4;

  const float* X; float* G; int N, ti, tj, k0base; bool modeA;
  int b = blockIdx.x;
  if (b < 512) {
    modeA = true; X = W1; G = G1p; N = 512;
    int s = b >> 6, t = b & 63;
    ti = t >> 3; tj = t & 7; k0base = s * 128;
  } else {
    modeA = false; b -= 512; X = W2; G = G2; N = 256;
    int s = b >> 4, t = b & 15;
    ti = t >> 2; tj = t & 3; k0base = s * 128;
  }

  float acc[4][4] = {};
  for (int k0 = k0base; k0 < k0base + 128; k0 += 32) {
    if (modeA) {
      for (int idx = tid; idx < 2048; idx += 256) {
        int r = idx & 63, c = idx >> 6;
        As[c][r] = X[(size_t)(k0 + c) * 512 + ti * 64 + r];
        Bs[c][r] = X[(size_t)(k0 + c) * 512 + tj * 64 + r];
      }
    } else {
      for (int idx = tid; idx < 2048; idx += 256) {
        int c = idx & 31, r = idx >> 5;
        As[c][r] = X[(size_t)(ti * 64 + r) * 1024 + k0 + c];
        Bs[c][r] = X[(size_t)(tj * 64 + r) * 1024 + k0 + c];
      }
    }
    __syncthreads();
#pragma unroll
    for (int kk = 0; kk < 32; kk++) {
      float a[4], bb[4];
#pragma unroll
      for (int i = 0; i < 4; i++) a[i] = As[kk][ty * 4 + i];
#pragma unroll
      for (int j = 0; j < 4; j++) bb[j] = Bs[kk][tx * 4 + j];
#pragma unroll
      for (int i = 0; i < 4; i++)
#pragma unroll
        for (int j = 0; j < 4; j++) acc[i][j] += a[i] * bb[j];
    }
    __syncthreads();
  }
#pragma unroll
  for (int i = 0; i < 4; i++)
#pragma unroll
    for (int j = 0; j < 4; j++)
      atomicAdd(&G[(size_t)(ti * 64 + ty * 4 + i) * N + tj * 64 + tx * 4 + j],
                acc[i][j]);
}

// ---------------- colsum: vA += W1^T ones (verified) -----------------------
__global__ __launch_bounds__(256) void colsum_kernel(
    const float* __restrict__ W1, float* __restrict__ vA) {
  int b = blockIdx.x;
  for (int c = threadIdx.x; c < KCAT; c += 256) {
    float s = 0.f;
#pragma unroll
    for (int r = 0; r < 16; r++) s += W1[(size_t)(16 * b + r) * KCAT + c];
    atomicAdd(&vA[c], s);
  }
}

// ---------------- squaring, split-K: out += scale * (in.in^T partial) ------
// blocks 0..511: 512-matrix, 64 tiles x 8 K-splits; 512..575: 256-matrix,
// 16 tiles x 4 K-splits. K-split width 64. Requires zero-inited outputs.
__global__ __launch_bounds__(256) void sq_kernel(
    const float* __restrict__ in1, float* __restrict__ out1,
    const float* __restrict__ in2, float* __restrict__ out2, float scale) {
  __shared__ float As[32][65];
  __shared__ float Bs[32][65];
  const int tid = threadIdx.x;
  const int tx = tid & 15, ty = tid >> 4;

  const float* X; float* S; int N, ti, tj, k0base;
  int b = blockIdx.x;
  if (b < 512) {
    X = in1; S = out1; N = 512;
    int t = b & 63; ti = t >> 3; tj = t & 7; k0base = (b >> 6) * 64;
  } else {
    b -= 512; X = in2; S = out2; N = 256;
    int t = b & 15; ti = t >> 2; tj = t & 3; k0base = (b >> 4) * 64;
  }

  float acc[4][4] = {};
  for (int k0 = k0base; k0 < k0base + 64; k0 += 32) {
    for (int idx = tid; idx < 2048; idx += 256) {
      int c = idx & 31, r = idx >> 5;
      As[c][r] = X[(size_t)(ti * 64 + r) * N + k0 + c];
      Bs[c][r] = X[(size_t)(tj * 64 + r) * N + k0 + c];
    }
    __syncthreads();
#pragma unroll
    for (int kk = 0; kk < 32; kk++) {
      float a[4], bb[4];
#pragma unroll
      for (int i = 0; i < 4; i++) a[i] = As[kk][ty * 4 + i];
#pragma unroll
      for (int j = 0; j < 4; j++) bb[j] = Bs[kk][tx * 4 + j];
#pragma unroll
      for (int i = 0; i < 4; i++)
#pragma unroll
        for (int j = 0; j < 4; j++) acc[i][j] += a[i] * bb[j];
    }
    __syncthreads();
  }
#pragma unroll
  for (int i = 0; i < 4; i++)
#pragma unroll
    for (int j = 0; j < 4; j++)
      atomicAdd(&S[(size_t)(ti * 64 + ty * 4 + i) * N + tj * 64 + tx * 4 + j],
                scale * acc[i][j]);
}

// ---------------- joint matvec (verified r9) -------------------------------
__global__ __launch_bounds__(256) void mv_kernel(
    const float* __restrict__ Pv, const float* __restrict__ xvi,
    float* __restrict__ xvo, float sv, const float* __restrict__ Pu,
    const float* __restrict__ xui, float* __restrict__ xuo, float su,
    int u_active) {
  int gw = blockIdx.x * 4 + (threadIdx.x >> 6);
  int lane = threadIdx.x & 63;
  const float* P; const float* xin; float* xout; float s; int n, r;
  if (gw < 512) {
    P = Pv; xin = xvi; xout = xvo; s = sv; n = 512; r = gw;
  } else {
    if (!u_active) return;
    P = Pu; xin = xui; xout = xuo; s = su; n = 256; r = gw - 512;
  }
  const float4* Pr = (const float4*)(P + (size_t)r * n);
  const float4* xv = (const float4*)xin;
  float acc = 0.f;
  for (int c = lane; c < (n >> 2); c += 64) {
    float4 g = Pr[c], u = xv[c];
    acc += g.x * u.x + g.y * u.y + g.z * u.z + g.w * u.w;
  }
  for (int off = 32; off; off >>= 1) acc += __shfl_down(acc, off, 64);
  if (lane == 0) xout[r] = s * acc;
}

// ---------------- sigma (damp = 1/8, verified r9) --------------------------
__global__ __launch_bounds__(256) void sigma_kernel(
    const float* __restrict__ v20, const float* __restrict__ v19,
    const float* __restrict__ u20, const float* __restrict__ u21,
    float* __restrict__ sig) {
  float s[4] = {0.f, 0.f, 0.f, 0.f};
  for (int i = threadIdx.x; i < KCAT; i += 256) {
    s[0] += v20[i] * v19[i];
    s[1] += v20[i] * v20[i];
  }
  for (int i = threadIdx.x; i < D_LAT; i += 256) {
    s[2] += u20[i] * u20[i];
    s[3] += u20[i] * u21[i];
  }
  __shared__ float red[4][4];
  int lane = threadIdx.x & 63, w = threadIdx.x >> 6;
  for (int k = 0; k < 4; k++) {
    float a = s[k];
    for (int off = 32; off; off >>= 1) a += __shfl_down(a, off, 64);
    if (lane == 0) red[k][w] = a;
  }
  __syncthreads();
  if (threadIdx.x == 0) {
    float d0 = red[0][0] + red[0][1] + red[0][2] + red[0][3];
    float d1 = red[1][0] + red[1][1] + red[1][2] + red[1][3];
    float d2 = red[2][0] + red[2][1] + red[2][2] + red[2][3];
    float d3 = red[3][0] + red[3][1] + red[3][2] + red[3][3];
    sig[0] = sqrtf(0.125f * d0 / d1);
    sig[1] = sqrtf(0.125f * d2 / d3);
  }
}

// ---------------- fold sigma into bf16 weights (verified) ------------------
__global__ void wfold_kernel(const float* __restrict__ W1,
                             const float* __restrict__ W2,
                             const float* __restrict__ sig,
                             __hip_bfloat16* __restrict__ W1b,
                             __hip_bfloat16* __restrict__ W2b) {
  int i = blockIdx.x * 256 + threadIdx.x;
  if (i < D_HID * KCAT) W1b[i] = __float2bfloat16(W1[i] * sig[0]);
  int j = i - D_HID * KCAT;
  if (j >= 0 && j < D_LAT * D_HID) W2b[j] = __float2bfloat16(W2[j] * sig[1]);
}

// ---------------- device: anderson for one row (verified math) -------------
__device__ __forceinline__ void anderson_row(
    const float* Xh, const float* Fh, int tpos, int mk, int row, int lane,
    float xout[4]) {
  const size_t base = (size_t)row * D_LAT + lane;
  float fa[4], xa[4], r[4], Fm1[4];
  {
    int sx = rdslot(tpos - 1);
#pragma unroll
    for (int c = 0; c < 4; c++) {
      fa[c] = Fh[(size_t)sx * SLOT + base + 64 * c];
      xa[c] = Xh[(size_t)sx * SLOT + base + 64 * c];
      r[c] = fa[c] - xa[c];
      Fm1[c] = fa[c];
    }
  }

  float dF[5][4], dG[5][4];
  for (int i = 1; i <= mk; i++) {
    int s = rdslot(tpos - 1 - i);
#pragma unroll
    for (int c = 0; c < 4; c++) {
      float fb = Fh[(size_t)s * SLOT + base + 64 * c];
      float xb = Xh[(size_t)s * SLOT + base + 64 * c];
      dF[i - 1][c] = fa[c] - fb;
      float dx = xa[c] - xb;
      dG[i - 1][c] = dF[i - 1][c] - dx;
      fa[c] = fb;
      xa[c] = xb;
    }
  }

  float vals[20];
  int nv = 0;
  for (int i = 0; i < mk; i++)
    for (int j = i; j < mk; j++) {
      float s = 0.f;
#pragma unroll
      for (int c = 0; c < 4; c++) s += dG[i][c] * dG[j][c];
      vals[nv++] = s;
    }
  for (int i = 0; i < mk; i++) {
    float s = 0.f;
#pragma unroll
    for (int c = 0; c < 4; c++) s += dG[i][c] * r[c];
    vals[nv++] = s;
  }
  for (int off = 1; off <= 32; off <<= 1)
    for (int v = 0; v < nv; v++) vals[v] += __shfl_xor(vals[v], off, 64);

  double A[5][5], bv[5], alpha[5];
  int p = 0;
  for (int i = 0; i < mk; i++)
    for (int j = i; j < mk; j++) {
      A[i][j] = (double)vals[p];
      A[j][i] = (double)vals[p];
      p++;
    }
  for (int i = 0; i < mk; i++) A[i][i] += (double)1e-4f;
  for (int i = 0; i < mk; i++) bv[i] = (double)vals[p++];

  for (int c = 0; c < mk; c++) {
    double inv = 1.0 / A[c][c];
    for (int rw = c + 1; rw < mk; rw++) {
      double fct = A[rw][c] * inv;
      for (int cc = c; cc < mk; cc++) A[rw][cc] -= fct * A[c][cc];
      bv[rw] -= fct * bv[c];
    }
  }
  for (int i = mk - 1; i >= 0; i--) {
    double s = bv[i];
    for (int j = i + 1; j < mk; j++) s -= A[i][j] * alpha[j];
    alpha[i] = s / A[i][i];
  }

#pragma unroll
  for (int c = 0; c < 4; c++) {
    float x = Fm1[c];
    for (int i = 0; i < mk; i++) x -= dF[i][c] * (float)alpha[i];
    xout[c] = x;
  }
}

// ---------------- andergemm1: anderson prologue + verified BK=64 gemm1 -----
// grid (32, 8). mode 0: no phase A (x0 path). mode 1: X1 = F0 copy.
// mode 2: anderson(tpos) -> Xh[tpos%7] + zc. Then hb = tanh(zc@W1b^T + b1).
__global__ __launch_bounds__(256) void andergemm1_kernel(
    __hip_bfloat16* zc, const __hip_bfloat16* __restrict__ W1b,
    const float* __restrict__ b1, __hip_bfloat16* __restrict__ hb,
    float* Xh, const float* __restrict__ Fh, int tpos, int mode) {
  constexpr int BM = 64, BN = 128;
  __shared__ __align__(16) u16 lds[(BM + BN) * 64];
  u16* As = lds;
  u16* Ws = lds + BM * 64;
  const int tid = threadIdx.x;
  const int lane = tid & 63;
  const int wid = tid >> 6;
  const int bm = blockIdx.x * BM;

  // ---- phase A (redundant across blockIdx.y; race-free-by-value) ----------
  if (mode == 1) {
    // X1 = F0; zc = bf16(F0) for own rows
    for (int rr = 0; rr < 16; rr++) {
      int row = bm + wid * 16 + rr;
      size_t base = (size_t)row * D_LAT + lane;
#pragma unroll
      for (int c = 0; c < 4; c++) {
        float v = Fh[base + 64 * c];
        Xh[SLOT + base + 64 * c] = v;
        zc[(size_t)row * KCAT + lane + 64 * c] = __float2bfloat16(v);
      }
    }
    __syncthreads();
  } else if (mode == 2) {
    const int mk = (tpos - 1 < 5) ? (tpos - 1) : 5;
    float* Xw = Xh + (size_t)(tpos % NRING) * SLOT;
    for (int rr = 0; rr < 16; rr++) {
      int row = bm + wid * 16 + rr;
      float xo[4];
      anderson_row(Xh, Fh, tpos, mk, row, lane, xo);
      size_t base = (size_t)row * D_LAT + lane;
#pragma unroll
      for (int c = 0; c < 4; c++) {
        Xw[base + 64 * c] = xo[c];
        zc[(size_t)row * KCAT + lane + 64 * c] = __float2bfloat16(xo[c]);
      }
    }
    __syncthreads();  // drains vmcnt: zc stores visible to global_load_lds
  }

  // ---- phase B: verbatim r5 BK=64 gemm1 -----------------------------------
  const int wy = wid >> 1, wx = wid & 1;
  constexpr int WM = BM / 2, WN = BN / 2;
  constexpr int MB = WM / 16, NB = WN / 16;
  const int bn = blockIdx.y * BN;
  const int rlo = lane & 15, quad = lane >> 4;

  f32x4 acc[MB][NB] = {};

  for (int k0 = 0; k0 < KCAT; k0 += 64) {
    for (int c = tid; c < BM * 8; c += 256) {
      int r = c >> 3, o = (c & 7) ^ (r & 7);
      __builtin_amdgcn_global_load_lds(
          (const AS1 void*)(zc + (size_t)(bm + r) * KCAT + k0 + o * 8),
          (AS3 void*)(As + c * 8), 16, 0, 0);
    }
    for (int c = tid; c < BN * 8; c += 256) {
      int r = c >> 3, o = (c & 7) ^ (r & 7);
      __builtin_amdgcn_global_load_lds(
          (const AS1 void*)(W1b + (size_t)(bn + r) * KCAT + k0 + o * 8),
          (AS3 void*)(Ws + c * 8), 16, 0, 0);
    }
    __syncthreads();
#pragma unroll
    for (int kk = 0; kk < 2; kk++) {
      bf16x8 af[MB], bfr[NB];
#pragma unroll
      for (int mb = 0; mb < MB; mb++) {
        int r = wy * WM + mb * 16 + rlo;
        int o = (kk * 4 + quad) ^ (r & 7);
        af[mb] = *(const bf16x8*)(As + (r * 8 + o) * 8);
      }
#pragma unroll
      for (int nb = 0; nb < NB; nb++) {
        int r = wx * WN + nb * 16 + rlo;
        int o = (kk * 4 + quad) ^ (r & 7);
        bfr[nb] = *(const bf16x8*)(Ws + (r * 8 + o) * 8);
      }
#pragma unroll
      for (int mb = 0; mb < MB; mb++)
#pragma unroll
        for (int nb = 0; nb < NB; nb++)
          acc[mb][nb] = __builtin_amdgcn_mfma_f32_16x16x32_bf16(
              af[mb], bfr[nb], acc[mb][nb], 0, 0, 0);
    }
    __syncthreads();
  }

#pragma unroll
  for (int mb = 0; mb < MB; mb++) {
#pragma unroll
    for (int nb = 0; nb < NB; nb++) {
      int n = bn + wx * WN + nb * 16 + rlo;
      float bv = b1[n];
#pragma unroll
      for (int rg = 0; rg < 4; rg++) {
        int m = bm + wy * WM + mb * 16 + quad * 4 + rg;
        float val = tanhf(acc[mb][nb][rg] + bv);
        hb[(size_t)m * D_HID + n] = __float2bfloat16(val);
      }
    }
  }
}

// ---------------- gemm2 (verified r5 BK=64, BM=64 BN=64) -------------------
__global__ __launch_bounds__(256) void gemm2_kernel(
    const __hip_bfloat16* __restrict__ A, const __hip_bfloat16* __restrict__ W,
    const float* __restrict__ bias, float* __restrict__ Cf) {
  constexpr int BM = 64, BN = 64, K = D_HID, N = D_LAT;
  __shared__ __align__(16) u16 lds[(BM + BN) * 64];
  u16* As = lds;
  u16* Ws = lds + BM * 64;
  const int tid = threadIdx.x;
  const int lane = tid & 63;
  const int wid = tid >> 6;
  const int wy = wid >> 1, wx = wid & 1;
  constexpr int WM = BM / 2, WN = BN / 2;
  constexpr int MB = WM / 16, NB = WN / 16;
  const int bm = blockIdx.x * BM;
  const int bn = blockIdx.y * BN;
  const int rlo = lane & 15, quad = lane >> 4;

  f32x4 acc[MB][NB] = {};

  for (int k0 = 0; k0 < K; k0 += 64) {
    for (int c = tid; c < BM * 8; c += 256) {
      int r = c >> 3, o = (c & 7) ^ (r & 7);
      __builtin_amdgcn_global_load_lds(
          (const AS1 void*)(A + (size_t)(bm + r) * K + k0 + o * 8),
          (AS3 void*)(As + c * 8), 16, 0, 0);
    }
    for (int c = tid; c < BN * 8; c += 256) {
      int r = c >> 3, o = (c & 7) ^ (r & 7);
      __builtin_amdgcn_global_load_lds(
          (const AS1 void*)(W + (size_t)(bn + r) * K + k0 + o * 8),
          (AS3 void*)(Ws + c * 8), 16, 0, 0);
    }
    __syncthreads();
#pragma unroll
    for (int kk = 0; kk < 2; kk++) {
      bf16x8 af[MB], bfr[NB];
#pragma unroll
      for (int mb = 0; mb < MB; mb++) {
        int r = wy * WM + mb * 16 + rlo;
        int o = (kk * 4 + quad) ^ (r & 7);
        af[mb] = *(const bf16x8*)(As + (r * 8 + o) * 8);
      }
#pragma unroll
      for (int nb = 0; nb < NB; nb++) {
        int r = wx * WN + nb * 16 + rlo;
        int o = (kk * 4 + quad) ^ (r & 7);
        bfr[nb] = *(const bf16x8*)(Ws + (r * 8 + o) * 8);
      }
#pragma unroll
      for (int mb = 0; mb < MB; mb++)
#pragma unroll
        for (int nb = 0; nb < NB; nb++)
          acc[mb][nb] = __builtin_amdgcn_mfma_f32_16x16x32_bf16(
              af[mb], bfr[nb], acc[mb][nb], 0, 0, 0);
    }
    __syncthreads();
  }

#pragma unroll
  for (int mb = 0; mb < MB; mb++) {
#pragma unroll
    for (int nb = 0; nb < NB; nb++) {
      int n = bn + wx * WN + nb * 16 + rlo;
      float bv = bias[n];
#pragma unroll
      for (int rg = 0; rg < 4; rg++) {
        int m = bm + wy * WM + mb * 16 + quad * 4 + rg;
        Cf[(size_t)m * N + n] = tanhf(acc[mb][nb][rg] + bv);
      }
    }
  }
}

// ---------------- final anderson (t=25) -> out (verified structure) --------
__global__ __launch_bounds__(256) void anderson_final_kernel(
    const float* __restrict__ Xh, const float* __restrict__ Fh,
    float* __restrict__ out) {
  const int lane = threadIdx.x & 63;
  const int wid = threadIdx.x >> 6;
  const int row = blockIdx.x * 4 + wid;
  float xo[4];
  anderson_row(Xh, Fh, 25, 5, row, lane, xo);
  size_t base = (size_t)row * D_LAT + lane;
#pragma unroll
  for (int c = 0; c < 4; c++) out[base + 64 * c] = xo[c];
}

// ---------------- host orchestration ---------------------------------------
extern "C" void kernel_launch(void* const* d_in, const int* in_sizes, int n_in,
                              void* d_out, int out_size, void* d_ws,
                              size_t ws_size, hipStream_t stream) {
  const float* ctx = (const float*)d_in[0];
  const float* W1 = (const float*)d_in[1];
  const float* b1 = (const float*)d_in[2];
  const float* W2 = (const float*)d_in[3];
  const float* b2 = (const float*)d_in[4];
  float* out = (float*)d_out;

  float* ws = (float*)d_ws;
  float* sig = ws;                        // 16
  float* vA = ws + 16;                    // 512
  float* vB = vA + KCAT;                  // 512
  float* uA = vB + KCAT;                  // 256
  float* uB = uA + D_LAT;                 // 256
  float* G1p = uB + D_LAT;                // 512*512
  float* G2 = G1p + KCAT * KCAT;          // 256*256
  float* T1 = G2 + D_LAT * D_LAT;         // 512*512
  float* M1 = T1 + KCAT * KCAT;           // 512*512
  float* T2 = M1 + KCAT * KCAT;           // 256*256
  float* M2 = T2 + D_LAT * D_LAT;         // 256*256
  float* Xh = M2 + D_LAT * D_LAT;         // 7*SLOT
  float* Fh = Xh + NRING * SLOT;          // 7*SLOT
  __hip_bfloat16* W1b = (__hip_bfloat16*)(Fh + NRING * SLOT);  // 524288
  __hip_bfloat16* W2b = W1b + D_HID * KCAT;                    // 262144
  __hip_bfloat16* zc = W2b + D_LAT * D_HID;                    // 2048*512
  __hip_bfloat16* hb = zc + B_ROWS * KCAT;                     // 2048*1024

  // spectral setup
  init_kernel<<<4096, 256, 0, stream>>>(ctx, zc, G1p, G2, T1, M1, T2, M2, Xh,
                                        vA, uA);
  gram_kernel<<<640, 256, 0, stream>>>(W1, W2, G1p, G2);
  colsum_kernel<<<64, 256, 0, stream>>>(W1, vA);
  sq_kernel<<<576, 256, 0, stream>>>(G1p, T1, G2, T2, 0.015625f);
  sq_kernel<<<576, 256, 0, stream>>>(T1, M1, T2, M2, 1.0f);
  {
    const float kE = 0.125f;
    const float* Pv[8] = {G1p, G1p, G1p, M1, M1, M1, M1, G1p};
    float svs[8] = {kE, kE, kE, 1.f, 1.f, 1.f, 1.f, kE};
    const float* Pu[8] = {M2, M2, M2, M2, M2, G2, nullptr, nullptr};
    float sus[8] = {1.f, 1.f, 1.f, 1.f, 1.f, kE, 0.f, 0.f};
    for (int i = 0; i < 8; i++) {
      const float* vi = (i & 1) ? vB : vA;
      float* vo = (i & 1) ? vA : vB;
      const float* ui = (i & 1) ? uB : uA;
      float* uo = (i & 1) ? uA : uB;
      mv_kernel<<<192, 256, 0, stream>>>(Pv[i], vi, vo, svs[i], Pu[i], ui, uo,
                                         sus[i], i < 6);
    }
  }
  sigma_kernel<<<1, 256, 0, stream>>>(vA, vB, uB, uA, sig);
  wfold_kernel<<<3072, 256, 0, stream>>>(W1, W2, sig, W1b, W2b);

  // eval0 (x0 = 0): F0 -> slot 0
  andergemm1_kernel<<<dim3(32, 8), 256, 0, stream>>>(zc, W1b, b1, hb, Xh, Fh,
                                                     0, 0);
  gemm2_kernel<<<dim3(32, 4), 256, 0, stream>>>(hb, W2b, b2, Fh);
  // eval1 (X1 = F0): F1 -> slot 1; phantom pos2 handled by rdslot
  andergemm1_kernel<<<dim3(32, 8), 256, 0, stream>>>(zc, W1b, b1, hb, Xh, Fh,
                                                     0, 1);
  gemm2_kernel<<<dim3(32, 4), 256, 0, stream>>>(hb, W2b, b2, Fh + SLOT);
  // t = 3..24: anderson(t) + eval f(X[t]) -> F[t]
  for (int t = 3; t <= 24; t++) {
    andergemm1_kernel<<<dim3(32, 8), 256, 0, stream>>>(zc, W1b, b1, hb, Xh, Fh,
                                                       t, 2);
    gemm2_kernel<<<dim3(32, 4), 256, 0, stream>>>(
        hb, W2b, b2, Fh + (size_t)(t % NRING) * SLOT);
  }
  // final anderson (t=25) -> out
  anderson_final_kernel<<<512, 256, 0, stream>>>(Xh, Fh, out);
}